// Round 2
// baseline (2033.764 us; speedup 1.0000x reference)
//
#include <hip/hip_runtime.h>
#include <hip/hip_bf16.h>
#include <math.h>

// Problem constants (from reference)
constexpr int N = 100000;    // nodes
constexpr int E = 3200000;   // edges
constexpr int FIN = 128, H1 = 64, H2 = 32, COUT = 2;

// Bucketing: 64 dst-nodes per bucket, fixed-capacity slices
constexpr int BUK_SHIFT = 6;
constexpr int BUK_NODES = 64;                          // 1 << BUK_SHIFT
constexpr int NBUK = (N + BUK_NODES - 1) / BUK_NODES;  // 1563
constexpr int CAP = 2560;             // slice capacity; mean fill 2048, sigma~45
// src segmentation: seg = src >> 14 (16384 rows = 2 MB of y1 bf16). Edges are
// stored SEG-MAJOR within each bucket (key = seg*64 + ld): per-(bucket,seg)
// runs are contiguous, so the aggregate sweeps segments in explicit phases
// (all blocks co-resident & phase-aligned -> ~2MB gather working set, L2-hit)
// while consuming each run EDGE-PARALLEL for deep MLP (R1 lesson: per-node
// per-seg sublists are ~4.6 edges -> latency-bound).
constexpr int SEG_SHIFT = 14;
constexpr int NSEG = 7;
constexpr int KEYS = NSEG * BUK_NODES;                 // 448 (seg-major!)
constexpr int RP2_STR = KEYS + 1;                      // 449 rowptr slots/bucket

constexpr int MS_TPB = 1024;
constexpr int MS_EPT = 24;                             // edges per thread
constexpr int CHUNK = MS_TPB * MS_EPT;                 // 24576
constexpr int MS_WGS = (E + CHUNK - 1) / CHUNK;        // 131

// ---------------- init: gcursor[b] = b*CAP ----------------
__global__ void k_initcur(int* __restrict__ gcursor) {
    int i = blockIdx.x * blockDim.x + threadIdx.x;
    if (i < NBUK) gcursor[i] = i * CAP;
}

// ---------------- multisplit into fixed-capacity bucket slices ----------------
// packed entry: src (17 bits) | local_node (6 bits) << 17
__global__ __launch_bounds__(MS_TPB)
void k_mslice(const int* __restrict__ src, const int* __restrict__ dst,
              int* __restrict__ gcursor, unsigned* __restrict__ ebuf) {
    __shared__ int cnt[NBUK];
    __shared__ int base[NBUK];
    const int t = threadIdx.x;
    for (int i = t; i < NBUK; i += MS_TPB) cnt[i] = 0;
    __syncthreads();
    const int e0 = blockIdx.x * CHUNK;

    int rb[MS_EPT];
    unsigned rv[MS_EPT];
#pragma unroll
    for (int j = 0; j < MS_EPT; ++j) {
        int e = e0 + j * MS_TPB + t;
        if (e < E) {
            int d = dst[e];
            int b = d >> BUK_SHIFT;
            rb[j] = b;
            rv[j] = (unsigned)src[e] | ((unsigned)(d & (BUK_NODES - 1)) << 17);
            atomicAdd(&cnt[b], 1);
        } else {
            rb[j] = -1; rv[j] = 0;
        }
    }
    __syncthreads();
    for (int i = t; i < NBUK; i += MS_TPB) {
        int c = cnt[i];
        base[i] = c ? atomicAdd(&gcursor[i], c) : 0;
    }
    __syncthreads();
    for (int i = t; i < NBUK; i += MS_TPB) cnt[i] = 0;
    __syncthreads();
#pragma unroll
    for (int j = 0; j < MS_EPT; ++j) {
        int b = rb[j];
        if (b >= 0) {
            int r = atomicAdd(&cnt[b], 1);
            int p = base[b] + r;
            if (p < (b + 1) * CAP) ebuf[p] = rv[j];   // overflow guard (statistically impossible)
        }
    }
}

// ---------------- per-bucket build: counting-sort by (seg, local_dst) ----------------
// SEG-MAJOR key => per-(bucket,seg) runs contiguous. Entries KEEP the ld tag
// (src | ld<<17) so the edge-parallel aggregate reads dst per edge.
// Emits full rowptr rp2[b*449 + key] for all 448 keys + sentinel; dinv.
__global__ __launch_bounds__(256)
void k_build(const int* __restrict__ gcursor, unsigned* __restrict__ ebuf,
             int* __restrict__ rp2, float* __restrict__ dinv) {
    __shared__ unsigned ent[CAP];
    __shared__ int cnt[512];
    __shared__ int sa[512];
    __shared__ int sb[512];
    __shared__ int cur[512];
    const int b = blockIdx.x;
    const int t = threadIdx.x;
    int fill = gcursor[b] - b * CAP;
    if (fill > CAP) fill = CAP;
    const int gbase = b * CAP;

    cnt[t] = 0; cnt[t + 256] = 0;
    __syncthreads();
    for (int j = t; j < fill; j += 256) {
        unsigned v = ebuf[gbase + j];
        ent[j] = v;
        int key = (int)((v & 0x1FFFFu) >> SEG_SHIFT) * BUK_NODES + (int)(v >> 17);
        atomicAdd(&cnt[key], 1);
    }
    __syncthreads();
    sa[t] = cnt[t]; sa[t + 256] = cnt[t + 256];
    __syncthreads();
    int* pin = sa; int* pout = sb;
    for (int off = 1; off < 512; off <<= 1) {
        pout[t]       = pin[t]       + ((t >= off)       ? pin[t - off]       : 0);
        pout[t + 256] = pin[t + 256] + ((t + 256 >= off) ? pin[t + 256 - off] : 0);
        __syncthreads();
        int* tmp = pin; pin = pout; pout = tmp;
    }
    {
        int ex0 = pin[t] - cnt[t];
        int ex1 = pin[t + 256] - cnt[t + 256];
        cur[t] = gbase + ex0;
        cur[t + 256] = gbase + ex1;
        if (t < KEYS) rp2[b * RP2_STR + t] = gbase + ex0;
        int k2 = t + 256;
        if (k2 < KEYS) rp2[b * RP2_STR + k2] = gbase + ex1;
        if (t == 0) rp2[b * RP2_STR + KEYS] = gbase + fill;   // sentinel
    }
    if (t < BUK_NODES) {
        int deg = 0;
#pragma unroll
        for (int s = 0; s < NSEG; ++s) deg += cnt[s * BUK_NODES + t];
        int node = (b << BUK_SHIFT) + t;
        if (node < N) dinv[node] = rsqrtf((float)deg + 1.0f);  // self-loop included
    }
    __syncthreads();
    for (int j = t; j < fill; j += 256) {
        unsigned v = ent[j];
        int key = (int)((v & 0x1FFFFu) >> SEG_SHIFT) * BUK_NODES + (int)(v >> 17);
        int p = atomicAdd(&cur[key], 1);
        ebuf[p] = v;   // sorted; KEEP ld tag for edge-parallel consumers
    }
}

// ---------------- register-tiled GEMM + dinv scale, bf16 output ----------------
template<int FI, int FO>
__global__ __launch_bounds__(256)
void k_gemm_tile_bf(const float* __restrict__ h, const float* __restrict__ Wg,
                    const float* __restrict__ dinv, __hip_bfloat16* __restrict__ y) {
    constexpr int TX  = FO / 4;
    constexpr int TY  = 256 / TX;
    constexpr int RPT = 64 / TY;
    constexpr int XS  = 68;
    constexpr int KQ  = FI / 4;

    __shared__ float xsT[FI][XS];

    const int tid = threadIdx.x;
    const int tx = tid % TX;
    const int ty = tid / TX;
    const int row0 = blockIdx.x * 64;

    for (int idx = tid; idx < 64 * KQ; idx += 256) {
        int g   = idx / 8;
        int rlo = idx % 8;
        int k4  = g % KQ;
        int rhi = g / KQ;
        int r   = rlo + 8 * rhi;
        int row = row0 + r;
        float4 v = make_float4(0.f, 0.f, 0.f, 0.f);
        if (row < N) v = *(const float4*)(h + (size_t)row * FI + 4 * k4);
        xsT[4 * k4 + 0][r] = v.x;
        xsT[4 * k4 + 1][r] = v.y;
        xsT[4 * k4 + 2][r] = v.z;
        xsT[4 * k4 + 3][r] = v.w;
    }
    __syncthreads();

    float acc[RPT][4];
#pragma unroll
    for (int i = 0; i < RPT; ++i)
#pragma unroll
        for (int c = 0; c < 4; ++c) acc[i][c] = 0.0f;

#pragma unroll 4
    for (int k = 0; k < FI; ++k) {
        const float4 wv = *(const float4*)(Wg + (size_t)k * FO + 4 * tx);
        float xv[RPT];
        if constexpr (RPT == 4) {
            float4 t = *(const float4*)&xsT[k][4 * ty];
            xv[0] = t.x; xv[1] = t.y; xv[2] = t.z; xv[3] = t.w;
        } else {
            float2 t = *(const float2*)&xsT[k][2 * ty];
            xv[0] = t.x; xv[1] = t.y;
        }
#pragma unroll
        for (int i = 0; i < RPT; ++i) {
            acc[i][0] = fmaf(xv[i], wv.x, acc[i][0]);
            acc[i][1] = fmaf(xv[i], wv.y, acc[i][1]);
            acc[i][2] = fmaf(xv[i], wv.z, acc[i][2]);
            acc[i][3] = fmaf(xv[i], wv.w, acc[i][3]);
        }
    }

#pragma unroll
    for (int i = 0; i < RPT; ++i) {
        int row = row0 + ty * RPT + i;
        if (row >= N) continue;
        float di = dinv[row];
        auto cvt = [](float f) -> unsigned short {
            __hip_bfloat16 b = __float2bfloat16(f);
            return *reinterpret_cast<unsigned short*>(&b);
        };
        ushort4 pk;
        pk.x = cvt(di * acc[i][0]);
        pk.y = cvt(di * acc[i][1]);
        pk.z = cvt(di * acc[i][2]);
        pk.w = cvt(di * acc[i][3]);
        *(ushort4*)&y[(size_t)row * FO + 4 * tx] = pk;
    }
}

// ---------------- fused GEMM + dinv scale, fp32 output (layer 3, tiny) ----------------
template<int FI, int FO, int ROWS>
__global__ __launch_bounds__(FO * ROWS)
void k_gemm_scale(const float* __restrict__ h, const float* __restrict__ W,
                  const float* __restrict__ dinv, float* __restrict__ y) {
    __shared__ float xs[ROWS][FI];
    const int j = threadIdx.x;
    const int r = threadIdx.y;
    const int row0 = blockIdx.x * ROWS;
    const int tid = r * FO + j;
    constexpr int NT = FO * ROWS;
    for (int t = tid; t < ROWS * FI; t += NT) {
        int rr = t / FI, kk = t % FI;
        int row = row0 + rr;
        xs[rr][kk] = (row < N) ? h[(size_t)row * FI + kk] : 0.0f;
    }
    __syncthreads();
    const int row = row0 + r;
    if (row >= N) return;
    float acc = 0.0f;
#pragma unroll
    for (int k = 0; k < FI; ++k)
        acc = fmaf(xs[r][k], W[k * FO + j], acc);
    y[(size_t)row * FO + j] = dinv[row] * acc;
}

// ---------------- edge-parallel phased aggregate (bf16 gather) ----------------
// Block = bucket. acc[64][F] in LDS. Per seg phase, the contiguous
// (bucket,seg) run is consumed edge-parallel: EPG edges in flight, unroll-4,
// LDS float atomics (lanes in one ds_add hit distinct addrs -> 2-way, free).
// All 1563 blocks co-resident (16KB LDS) -> phases stay time-aligned.
template<int F, bool RELU>
__global__ __launch_bounds__(256)
void k_agg_edge(const int* __restrict__ rp2, const unsigned* __restrict__ csr,
                const __hip_bfloat16* __restrict__ y, const float* __restrict__ dinv,
                const float* __restrict__ bias, float* __restrict__ out) {
    constexpr int LPN = F / 2;          // lanes per edge (feature pairs)
    constexpr int EPG = 256 / LPN;      // edges in flight (8 for F=64, 16 for F=32)
    __shared__ float acc[BUK_NODES][F];
    const int tid = threadIdx.x;
    const int fp  = tid & (LPN - 1);
    const int eg  = tid / LPN;
    const int b   = blockIdx.x;
    const int n0  = b << BUK_SHIFT;
    const unsigned* yw = (const unsigned*)y;

    auto load2 = [&](unsigned s) -> float2 {
        unsigned u = yw[(size_t)s * LPN + fp];
        float2 v;
        v.x = __uint_as_float(u << 16);
        v.y = __uint_as_float(u & 0xffff0000u);
        return v;
    };

    // init with self-loop row
    for (int i = tid; i < BUK_NODES * LPN; i += 256) {
        int nl = i / LPN, f2 = i & (LPN - 1);
        int n = n0 + nl;
        float2 v = make_float2(0.f, 0.f);
        if (n < N) {
            unsigned u = yw[(size_t)n * LPN + f2];
            v.x = __uint_as_float(u << 16);
            v.y = __uint_as_float(u & 0xffff0000u);
        }
        acc[nl][2 * f2]     = v.x;
        acc[nl][2 * f2 + 1] = v.y;
    }
    __syncthreads();

    const int rbase = b * RP2_STR;
    for (int s = 0; s < NSEG; ++s) {
        int j        = rp2[rbase + s * BUK_NODES] + eg;
        const int j1 = rp2[rbase + (s + 1) * BUK_NODES];   // s=6 -> sentinel
        for (; j + 3 * EPG < j1; j += 4 * EPG) {           // 4 gathers in flight/lane
            unsigned v0 = csr[j], v1 = csr[j + EPG], v2 = csr[j + 2 * EPG], v3 = csr[j + 3 * EPG];
            float2 a0 = load2(v0 & 0x1FFFFu), a1 = load2(v1 & 0x1FFFFu);
            float2 a2 = load2(v2 & 0x1FFFFu), a3 = load2(v3 & 0x1FFFFu);
            atomicAdd(&acc[v0 >> 17][2 * fp], a0.x); atomicAdd(&acc[v0 >> 17][2 * fp + 1], a0.y);
            atomicAdd(&acc[v1 >> 17][2 * fp], a1.x); atomicAdd(&acc[v1 >> 17][2 * fp + 1], a1.y);
            atomicAdd(&acc[v2 >> 17][2 * fp], a2.x); atomicAdd(&acc[v2 >> 17][2 * fp + 1], a2.y);
            atomicAdd(&acc[v3 >> 17][2 * fp], a3.x); atomicAdd(&acc[v3 >> 17][2 * fp + 1], a3.y);
        }
        for (; j < j1; j += EPG) {
            unsigned v = csr[j];
            float2 a = load2(v & 0x1FFFFu);
            atomicAdd(&acc[v >> 17][2 * fp],     a.x);
            atomicAdd(&acc[v >> 17][2 * fp + 1], a.y);
        }
        __syncthreads();   // phase alignment for the segment sweep
    }

    // epilogue: scale, bias, relu, store
    for (int i = tid; i < BUK_NODES * LPN; i += 256) {
        int nl = i / LPN, f2 = i & (LPN - 1);
        int n = n0 + nl;
        if (n < N) {
            float di = dinv[n];
            float o0 = fmaf(di, acc[nl][2 * f2],     bias[2 * f2]);
            float o1 = fmaf(di, acc[nl][2 * f2 + 1], bias[2 * f2 + 1]);
            if (RELU) { o0 = fmaxf(o0, 0.0f); o1 = fmaxf(o1, 0.0f); }
            *(float2*)&out[(size_t)n * F + 2 * f2] = make_float2(o0, o1);
        }
    }
}

// ---------------- layer 3 aggregate + log_softmax (edge-parallel, 2 classes) ----
// y3 is 0.8 MB -> L2-resident on every XCD; no seg phasing needed. Block =
// bucket, walk the whole slice edge-parallel: 128 edges in flight.
__global__ __launch_bounds__(256)
void k_final(const int* __restrict__ rp2, const unsigned* __restrict__ csr,
             const float* __restrict__ y, const float* __restrict__ dinv,
             const float* __restrict__ bias, float* __restrict__ out) {
    __shared__ float acc[BUK_NODES][2];
    const int tid = threadIdx.x;
    const int b = blockIdx.x;
    const int n0 = b << BUK_SHIFT;
    const int c = tid & 1;

    if (tid < 128) {
        int nl = tid >> 1;
        int n = n0 + nl;
        acc[nl][c] = (n < N) ? y[2 * n + c] : 0.0f;   // self-loop
    }
    __syncthreads();

    {
        const int eg = tid >> 1;   // 128 edge slots
        int j        = rp2[b * RP2_STR] + eg;
        const int j1 = rp2[b * RP2_STR + KEYS];
        for (; j + 384 < j1; j += 512) {
            unsigned v0 = csr[j], v1 = csr[j + 128], v2 = csr[j + 256], v3 = csr[j + 384];
            float a0 = y[2 * (v0 & 0x1FFFFu) + c], a1 = y[2 * (v1 & 0x1FFFFu) + c];
            float a2 = y[2 * (v2 & 0x1FFFFu) + c], a3 = y[2 * (v3 & 0x1FFFFu) + c];
            atomicAdd(&acc[v0 >> 17][c], a0);
            atomicAdd(&acc[v1 >> 17][c], a1);
            atomicAdd(&acc[v2 >> 17][c], a2);
            atomicAdd(&acc[v3 >> 17][c], a3);
        }
        for (; j < j1; j += 128) {
            unsigned v = csr[j];
            atomicAdd(&acc[v >> 17][c], y[2 * (v & 0x1FFFFu) + c]);
        }
    }
    __syncthreads();

    if (tid < 128) {
        int nl = tid >> 1;
        int n = n0 + nl;
        if (n < N) {
            float z = fmaf(dinv[n], acc[nl][c], bias[c]);
            float zo = __shfl_xor(z, 1);
            float m = fmaxf(z, zo);
            float lse = m + logf(expf(z - m) + expf(zo - m));
            out[2 * n + c] = z - lse;
        }
    }
}

extern "C" void kernel_launch(void* const* d_in, const int* in_sizes, int n_in,
                              void* d_out, int out_size, void* d_ws, size_t ws_size,
                              hipStream_t stream) {
    const float* x   = (const float*)d_in[0];
    const int*   ei  = (const int*)d_in[1];
    const float* W1  = (const float*)d_in[2];
    const float* b1  = (const float*)d_in[3];
    const float* W2  = (const float*)d_in[4];
    const float* b2  = (const float*)d_in[5];
    const float* W3  = (const float*)d_in[6];
    const float* b3  = (const float*)d_in[7];
    float* out = (float*)d_out;

    const int* src = ei;
    const int* dst = ei + E;

    // workspace layout
    char* p = (char*)d_ws;
    float*    dinv    = (float*)p;    p += (size_t)N * 4;
    int*      gcursor = (int*)p;      p += (size_t)NBUK * 4;
    int*      rp2     = (int*)p;      p += (size_t)NBUK * RP2_STR * 4;  // 2.8 MB
    unsigned* ebuf    = (unsigned*)p; p += (size_t)NBUK * CAP * 4;      // 16 MB
    char*     bufA    = p;            p += (size_t)N * 64 * 4;          // 25.6 MB
    char*     bufB    = p;            p += (size_t)N * 64 * 4;          // 25.6 MB

    __hip_bfloat16* y1 = (__hip_bfloat16*)bufA;     // N*64*2 B
    float*          h1 = (float*)bufB;              // N*64*4 B
    __hip_bfloat16* y2 = (__hip_bfloat16*)bufA;     // N*32*2 B (y1 dead)
    float*          h2 = (float*)(bufA + (size_t)N * H2 * 2);  // N*32*4 B
    float*          y3 = (float*)bufB;              // N*2*4 B (h1 dead)

    // ---- edge structure build ----
    k_initcur<<<(NBUK + 255) / 256, 256, 0, stream>>>(gcursor);
    k_mslice <<<MS_WGS, MS_TPB, 0, stream>>>(src, dst, gcursor, ebuf);
    k_build  <<<NBUK, 256, 0, stream>>>(gcursor, ebuf, rp2, dinv);

    // ---- layer 1: 128 -> 64 ----
    k_gemm_tile_bf<FIN, H1><<<(N + 63) / 64, 256, 0, stream>>>(x, W1, dinv, y1);
    k_agg_edge<H1, true><<<NBUK, 256, 0, stream>>>(rp2, ebuf, y1, dinv, b1, h1);

    // ---- layer 2: 64 -> 32 ----
    k_gemm_tile_bf<H1, H2><<<(N + 63) / 64, 256, 0, stream>>>(h1, W2, dinv, y2);
    k_agg_edge<H2, true><<<NBUK, 256, 0, stream>>>(rp2, ebuf, y2, dinv, b2, h2);

    // ---- layer 3: 32 -> 2 + log_softmax ----
    k_gemm_scale<H2, COUT, 128><<<(N + 127) / 128, dim3(COUT, 128), 0, stream>>>(h2, W3, dinv, y3);
    k_final<<<NBUK, 256, 0, stream>>>(rp2, ebuf, y3, dinv, b3, out);
}

// Round 3
// 665.551 us; speedup vs baseline: 3.0558x; 3.0558x over previous
//
#include <hip/hip_runtime.h>
#include <hip/hip_bf16.h>
#include <math.h>

// Problem constants (from reference)
constexpr int N = 100000;    // nodes
constexpr int E = 3200000;   // edges
constexpr int FIN = 128, H1 = 64, H2 = 32, COUT = 2;

// Bucketing: 64 dst-nodes per bucket, fixed-capacity slices
constexpr int BUK_SHIFT = 6;
constexpr int BUK_NODES = 64;                          // 1 << BUK_SHIFT
constexpr int NBUK = (N + BUK_NODES - 1) / BUK_NODES;  // 1563
constexpr int CAP = 2560;             // slice capacity; mean fill 2048, sigma~45
// src segmentation: seg = src >> 14 (16384 rows = 2 MB of y1 bf16). Edges are
// stored SEG-MAJOR within each bucket (key = seg*64 + ld): per-(bucket,seg)
// runs are contiguous AND ld-sorted. The aggregate sweeps segments in phases
// (all 1563 blocks co-resident & phase-aligned -> ~2MB gather working set,
// L2-hit; proven R1: FETCH 290->65MB) while consuming each run with per-lane
// contiguous chunks, 8 batched gathers in flight (proven R0 recipe), register
// run-accumulation, and rare LDS-atomic flushes at ld changes (avg run 4.6).
// R2 lesson: per-edge atomic consumption serializes (VGPR=12, VALUBusy 2%).
constexpr int SEG_SHIFT = 14;
constexpr int NSEG = 7;
constexpr int KEYS = NSEG * BUK_NODES;                 // 448 (seg-major!)
constexpr int RP2_STR = KEYS + 1;                      // 449 rowptr slots/bucket

constexpr int MS_TPB = 1024;
constexpr int MS_EPT = 24;                             // edges per thread
constexpr int CHUNK = MS_TPB * MS_EPT;                 // 24576
constexpr int MS_WGS = (E + CHUNK - 1) / CHUNK;        // 131

// ---------------- init: gcursor[b] = b*CAP ----------------
__global__ void k_initcur(int* __restrict__ gcursor) {
    int i = blockIdx.x * blockDim.x + threadIdx.x;
    if (i < NBUK) gcursor[i] = i * CAP;
}

// ---------------- multisplit into fixed-capacity bucket slices ----------------
// packed entry: src (17 bits) | local_node (6 bits) << 17
__global__ __launch_bounds__(MS_TPB)
void k_mslice(const int* __restrict__ src, const int* __restrict__ dst,
              int* __restrict__ gcursor, unsigned* __restrict__ ebuf) {
    __shared__ int cnt[NBUK];
    __shared__ int base[NBUK];
    const int t = threadIdx.x;
    for (int i = t; i < NBUK; i += MS_TPB) cnt[i] = 0;
    __syncthreads();
    const int e0 = blockIdx.x * CHUNK;

    int rb[MS_EPT];
    unsigned rv[MS_EPT];
#pragma unroll
    for (int j = 0; j < MS_EPT; ++j) {
        int e = e0 + j * MS_TPB + t;
        if (e < E) {
            int d = dst[e];
            int b = d >> BUK_SHIFT;
            rb[j] = b;
            rv[j] = (unsigned)src[e] | ((unsigned)(d & (BUK_NODES - 1)) << 17);
            atomicAdd(&cnt[b], 1);
        } else {
            rb[j] = -1; rv[j] = 0;
        }
    }
    __syncthreads();
    for (int i = t; i < NBUK; i += MS_TPB) {
        int c = cnt[i];
        base[i] = c ? atomicAdd(&gcursor[i], c) : 0;
    }
    __syncthreads();
    for (int i = t; i < NBUK; i += MS_TPB) cnt[i] = 0;
    __syncthreads();
#pragma unroll
    for (int j = 0; j < MS_EPT; ++j) {
        int b = rb[j];
        if (b >= 0) {
            int r = atomicAdd(&cnt[b], 1);
            int p = base[b] + r;
            if (p < (b + 1) * CAP) ebuf[p] = rv[j];   // overflow guard (statistically impossible)
        }
    }
}

// ---------------- per-bucket build: counting-sort by (seg, local_dst) ----------------
// SEG-MAJOR key => per-(bucket,seg) runs contiguous AND ld-sorted. Entries
// KEEP the ld tag (src | ld<<17) so consumers know the flush target.
// Emits full rowptr rp2[b*449 + key] for all 448 keys + sentinel; dinv.
__global__ __launch_bounds__(256)
void k_build(const int* __restrict__ gcursor, unsigned* __restrict__ ebuf,
             int* __restrict__ rp2, float* __restrict__ dinv) {
    __shared__ unsigned ent[CAP];
    __shared__ int cnt[512];
    __shared__ int sa[512];
    __shared__ int sb[512];
    __shared__ int cur[512];
    const int b = blockIdx.x;
    const int t = threadIdx.x;
    int fill = gcursor[b] - b * CAP;
    if (fill > CAP) fill = CAP;
    const int gbase = b * CAP;

    cnt[t] = 0; cnt[t + 256] = 0;
    __syncthreads();
    for (int j = t; j < fill; j += 256) {
        unsigned v = ebuf[gbase + j];
        ent[j] = v;
        int key = (int)((v & 0x1FFFFu) >> SEG_SHIFT) * BUK_NODES + (int)(v >> 17);
        atomicAdd(&cnt[key], 1);
    }
    __syncthreads();
    sa[t] = cnt[t]; sa[t + 256] = cnt[t + 256];
    __syncthreads();
    int* pin = sa; int* pout = sb;
    for (int off = 1; off < 512; off <<= 1) {
        pout[t]       = pin[t]       + ((t >= off)       ? pin[t - off]       : 0);
        pout[t + 256] = pin[t + 256] + ((t + 256 >= off) ? pin[t + 256 - off] : 0);
        __syncthreads();
        int* tmp = pin; pin = pout; pout = tmp;
    }
    {
        int ex0 = pin[t] - cnt[t];
        int ex1 = pin[t + 256] - cnt[t + 256];
        cur[t] = gbase + ex0;
        cur[t + 256] = gbase + ex1;
        if (t < KEYS) rp2[b * RP2_STR + t] = gbase + ex0;
        int k2 = t + 256;
        if (k2 < KEYS) rp2[b * RP2_STR + k2] = gbase + ex1;
        if (t == 0) rp2[b * RP2_STR + KEYS] = gbase + fill;   // sentinel
    }
    if (t < BUK_NODES) {
        int deg = 0;
#pragma unroll
        for (int s = 0; s < NSEG; ++s) deg += cnt[s * BUK_NODES + t];
        int node = (b << BUK_SHIFT) + t;
        if (node < N) dinv[node] = rsqrtf((float)deg + 1.0f);  // self-loop included
    }
    __syncthreads();
    for (int j = t; j < fill; j += 256) {
        unsigned v = ent[j];
        int key = (int)((v & 0x1FFFFu) >> SEG_SHIFT) * BUK_NODES + (int)(v >> 17);
        int p = atomicAdd(&cur[key], 1);
        ebuf[p] = v;   // sorted; KEEP ld tag
    }
}

// ---------------- register-tiled GEMM + dinv scale, bf16 output ----------------
template<int FI, int FO>
__global__ __launch_bounds__(256)
void k_gemm_tile_bf(const float* __restrict__ h, const float* __restrict__ Wg,
                    const float* __restrict__ dinv, __hip_bfloat16* __restrict__ y) {
    constexpr int TX  = FO / 4;
    constexpr int TY  = 256 / TX;
    constexpr int RPT = 64 / TY;
    constexpr int XS  = 68;
    constexpr int KQ  = FI / 4;

    __shared__ float xsT[FI][XS];

    const int tid = threadIdx.x;
    const int tx = tid % TX;
    const int ty = tid / TX;
    const int row0 = blockIdx.x * 64;

    for (int idx = tid; idx < 64 * KQ; idx += 256) {
        int g   = idx / 8;
        int rlo = idx % 8;
        int k4  = g % KQ;
        int rhi = g / KQ;
        int r   = rlo + 8 * rhi;
        int row = row0 + r;
        float4 v = make_float4(0.f, 0.f, 0.f, 0.f);
        if (row < N) v = *(const float4*)(h + (size_t)row * FI + 4 * k4);
        xsT[4 * k4 + 0][r] = v.x;
        xsT[4 * k4 + 1][r] = v.y;
        xsT[4 * k4 + 2][r] = v.z;
        xsT[4 * k4 + 3][r] = v.w;
    }
    __syncthreads();

    float acc[RPT][4];
#pragma unroll
    for (int i = 0; i < RPT; ++i)
#pragma unroll
        for (int c = 0; c < 4; ++c) acc[i][c] = 0.0f;

#pragma unroll 4
    for (int k = 0; k < FI; ++k) {
        const float4 wv = *(const float4*)(Wg + (size_t)k * FO + 4 * tx);
        float xv[RPT];
        if constexpr (RPT == 4) {
            float4 t = *(const float4*)&xsT[k][4 * ty];
            xv[0] = t.x; xv[1] = t.y; xv[2] = t.z; xv[3] = t.w;
        } else {
            float2 t = *(const float2*)&xsT[k][2 * ty];
            xv[0] = t.x; xv[1] = t.y;
        }
#pragma unroll
        for (int i = 0; i < RPT; ++i) {
            acc[i][0] = fmaf(xv[i], wv.x, acc[i][0]);
            acc[i][1] = fmaf(xv[i], wv.y, acc[i][1]);
            acc[i][2] = fmaf(xv[i], wv.z, acc[i][2]);
            acc[i][3] = fmaf(xv[i], wv.w, acc[i][3]);
        }
    }

#pragma unroll
    for (int i = 0; i < RPT; ++i) {
        int row = row0 + ty * RPT + i;
        if (row >= N) continue;
        float di = dinv[row];
        auto cvt = [](float f) -> unsigned short {
            __hip_bfloat16 b = __float2bfloat16(f);
            return *reinterpret_cast<unsigned short*>(&b);
        };
        ushort4 pk;
        pk.x = cvt(di * acc[i][0]);
        pk.y = cvt(di * acc[i][1]);
        pk.z = cvt(di * acc[i][2]);
        pk.w = cvt(di * acc[i][3]);
        *(ushort4*)&y[(size_t)row * FO + 4 * tx] = pk;
    }
}

// ---------------- fused GEMM + dinv scale, fp32 output (layer 3, tiny) ----------------
template<int FI, int FO, int ROWS>
__global__ __launch_bounds__(FO * ROWS)
void k_gemm_scale(const float* __restrict__ h, const float* __restrict__ W,
                  const float* __restrict__ dinv, float* __restrict__ y) {
    __shared__ float xs[ROWS][FI];
    const int j = threadIdx.x;
    const int r = threadIdx.y;
    const int row0 = blockIdx.x * ROWS;
    const int tid = r * FO + j;
    constexpr int NT = FO * ROWS;
    for (int t = tid; t < ROWS * FI; t += NT) {
        int rr = t / FI, kk = t % FI;
        int row = row0 + rr;
        xs[rr][kk] = (row < N) ? h[(size_t)row * FI + kk] : 0.0f;
    }
    __syncthreads();
    const int row = row0 + r;
    if (row >= N) return;
    float acc = 0.0f;
#pragma unroll
    for (int k = 0; k < FI; ++k)
        acc = fmaf(xs[r][k], W[k * FO + j], acc);
    y[(size_t)row * FO + j] = dinv[row] * acc;
}

// ---------------- phased run-accumulating aggregate (bf16 gather) ----------------
// Block = bucket. Per phase, the contiguous ld-sorted (bucket,seg) run is
// split into EPG contiguous chunks (one per lane-group). Each lane batches
// 8 csr words + 8 gathers into NAMED registers (keeps 8 loads in flight;
// R0-proven), accumulates run-wise in registers, flushes to padded SoA LDS
// accumulators via ds-atomic only on ld change (avg every 4.6 edges).
template<int F, bool RELU>
__global__ __launch_bounds__(256)
void k_agg_run(const int* __restrict__ rp2, const unsigned* __restrict__ csr,
               const __hip_bfloat16* __restrict__ y, const float* __restrict__ dinv,
               const float* __restrict__ bias, float* __restrict__ out) {
    constexpr int LPN = F / 2;          // lanes per edge (feature pairs)
    constexpr int EPG = 256 / LPN;      // lane-groups (8 for F=64, 16 for F=32)
    constexpr int PAD = LPN + 1;        // LDS row pad -> conflict-free flush
    __shared__ float xacc[BUK_NODES * PAD];
    __shared__ float yacc[BUK_NODES * PAD];
    const int tid = threadIdx.x;
    const int fp  = tid & (LPN - 1);
    const int eg  = tid / LPN;
    const int b   = blockIdx.x;
    const int n0  = b << BUK_SHIFT;
    const unsigned* yw = (const unsigned*)y;

    auto load2 = [&](unsigned v) -> float2 {
        unsigned u = yw[(size_t)(v & 0x1FFFFu) * LPN + fp];
        float2 r;
        r.x = __uint_as_float(u << 16);
        r.y = __uint_as_float(u & 0xffff0000u);
        return r;
    };

    // init with self-loop row
    for (int i = tid; i < BUK_NODES * LPN; i += 256) {
        int nl = i / LPN, f2 = i & (LPN - 1);
        int n = n0 + nl;
        float2 v = make_float2(0.f, 0.f);
        if (n < N) {
            unsigned u = yw[(size_t)n * LPN + f2];
            v.x = __uint_as_float(u << 16);
            v.y = __uint_as_float(u & 0xffff0000u);
        }
        xacc[nl * PAD + f2] = v.x;
        yacc[nl * PAD + f2] = v.y;
    }
    __syncthreads();

    int cur = -1;                 // carried across chunks/phases (commutative sums)
    float rx = 0.f, ry = 0.f;
    auto step = [&](unsigned v, float2 a) {
        int ld = (int)(v >> 17);
        if (ld != cur) {
            if (cur >= 0) {
                atomicAdd(&xacc[cur * PAD + fp], rx);
                atomicAdd(&yacc[cur * PAD + fp], ry);
            }
            cur = ld; rx = 0.f; ry = 0.f;
        }
        rx += a.x; ry += a.y;
    };

    const int rbase = b * RP2_STR;
    for (int s = 0; s < NSEG; ++s) {
        const int r0 = rp2[rbase + s * BUK_NODES];
        const int r1 = rp2[rbase + (s + 1) * BUK_NODES];   // s=6 -> sentinel
        const int len = r1 - r0;
        const int cl = (len + EPG - 1) / EPG;              // chunk length
        int j        = r0 + eg * cl;
        const int j1 = min(j + cl, r1);
        for (; j + 8 <= j1; j += 8) {
            // batch: 8 csr words then 8 gathers, all issued before any consumer
            unsigned e0 = csr[j],     e1 = csr[j + 1], e2 = csr[j + 2], e3 = csr[j + 3];
            unsigned e4 = csr[j + 4], e5 = csr[j + 5], e6 = csr[j + 6], e7 = csr[j + 7];
            float2 a0 = load2(e0), a1 = load2(e1), a2 = load2(e2), a3 = load2(e3);
            float2 a4 = load2(e4), a5 = load2(e5), a6 = load2(e6), a7 = load2(e7);
            step(e0, a0); step(e1, a1); step(e2, a2); step(e3, a3);
            step(e4, a4); step(e5, a5); step(e6, a6); step(e7, a7);
        }
        for (; j < j1; ++j) {
            unsigned e = csr[j];
            step(e, load2(e));
        }
        __syncthreads();   // phase alignment for the segment sweep
    }
    if (cur >= 0) {        // final flush of carried partial
        atomicAdd(&xacc[cur * PAD + fp], rx);
        atomicAdd(&yacc[cur * PAD + fp], ry);
    }
    __syncthreads();

    // epilogue: scale, bias, relu, store
    for (int i = tid; i < BUK_NODES * LPN; i += 256) {
        int nl = i / LPN, f2 = i & (LPN - 1);
        int n = n0 + nl;
        if (n < N) {
            float di = dinv[n];
            float o0 = fmaf(di, xacc[nl * PAD + f2], bias[2 * f2]);
            float o1 = fmaf(di, yacc[nl * PAD + f2], bias[2 * f2 + 1]);
            if (RELU) { o0 = fmaxf(o0, 0.0f); o1 = fmaxf(o1, 0.0f); }
            *(float2*)&out[(size_t)n * F + 2 * f2] = make_float2(o0, o1);
        }
    }
}

// ---------------- layer 3 aggregate + log_softmax (2 classes) ----------------
// y3 is 0.8 MB -> L2-resident everywhere; proven per-node walk, tag masked.
__global__ __launch_bounds__(256)
void k_final(const int* __restrict__ rp2, const unsigned* __restrict__ csr,
             const float* __restrict__ y, const float* __restrict__ dinv,
             const float* __restrict__ bias, float* __restrict__ out) {
    const int c = threadIdx.x;                       // class 0/1
    const int n = blockIdx.x * 128 + threadIdx.y;    // node
    float z = 0.0f;
    if (n < N) {
        const int base = (n >> BUK_SHIFT) * RP2_STR + (n & (BUK_NODES - 1));
        float acc = y[2 * n + c];
#pragma unroll
        for (int s = 0; s < NSEG; ++s) {
            int j        = rp2[base + s * BUK_NODES];
            const int j1 = rp2[base + s * BUK_NODES + 1];
            for (; j + 4 <= j1; j += 4) {
                int s0 = (int)(csr[j] & 0x1FFFFu),     s1 = (int)(csr[j + 1] & 0x1FFFFu);
                int s2 = (int)(csr[j + 2] & 0x1FFFFu), s3 = (int)(csr[j + 3] & 0x1FFFFu);
                float a0 = y[2 * s0 + c], a1 = y[2 * s1 + c];
                float a2 = y[2 * s2 + c], a3 = y[2 * s3 + c];
                acc += (a0 + a1) + (a2 + a3);
            }
            for (; j < j1; ++j) acc += y[2 * (int)(csr[j] & 0x1FFFFu) + c];
        }
        z = fmaf(dinv[n], acc, bias[c]);
    }
    float zo = __shfl_xor(z, 1);
    if (n < N) {
        float m = fmaxf(z, zo);
        float lse = m + logf(expf(z - m) + expf(zo - m));
        out[2 * n + c] = z - lse;
    }
}

extern "C" void kernel_launch(void* const* d_in, const int* in_sizes, int n_in,
                              void* d_out, int out_size, void* d_ws, size_t ws_size,
                              hipStream_t stream) {
    const float* x   = (const float*)d_in[0];
    const int*   ei  = (const int*)d_in[1];
    const float* W1  = (const float*)d_in[2];
    const float* b1  = (const float*)d_in[3];
    const float* W2  = (const float*)d_in[4];
    const float* b2  = (const float*)d_in[5];
    const float* W3  = (const float*)d_in[6];
    const float* b3  = (const float*)d_in[7];
    float* out = (float*)d_out;

    const int* src = ei;
    const int* dst = ei + E;

    // workspace layout
    char* p = (char*)d_ws;
    float*    dinv    = (float*)p;    p += (size_t)N * 4;
    int*      gcursor = (int*)p;      p += (size_t)NBUK * 4;
    int*      rp2     = (int*)p;      p += (size_t)NBUK * RP2_STR * 4;  // 2.8 MB
    unsigned* ebuf    = (unsigned*)p; p += (size_t)NBUK * CAP * 4;      // 16 MB
    char*     bufA    = p;            p += (size_t)N * 64 * 4;          // 25.6 MB
    char*     bufB    = p;            p += (size_t)N * 64 * 4;          // 25.6 MB

    __hip_bfloat16* y1 = (__hip_bfloat16*)bufA;     // N*64*2 B
    float*          h1 = (float*)bufB;              // N*64*4 B
    __hip_bfloat16* y2 = (__hip_bfloat16*)bufA;     // N*32*2 B (y1 dead)
    float*          h2 = (float*)(bufA + (size_t)N * H2 * 2);  // N*32*4 B
    float*          y3 = (float*)bufB;              // N*2*4 B (h1 dead)

    // ---- edge structure build ----
    k_initcur<<<(NBUK + 255) / 256, 256, 0, stream>>>(gcursor);
    k_mslice <<<MS_WGS, MS_TPB, 0, stream>>>(src, dst, gcursor, ebuf);
    k_build  <<<NBUK, 256, 0, stream>>>(gcursor, ebuf, rp2, dinv);

    // ---- layer 1: 128 -> 64 ----
    k_gemm_tile_bf<FIN, H1><<<(N + 63) / 64, 256, 0, stream>>>(x, W1, dinv, y1);
    k_agg_run<H1, true><<<NBUK, 256, 0, stream>>>(rp2, ebuf, y1, dinv, b1, h1);

    // ---- layer 2: 64 -> 32 ----
    k_gemm_tile_bf<H1, H2><<<(N + 63) / 64, 256, 0, stream>>>(h1, W2, dinv, y2);
    k_agg_run<H2, true><<<NBUK, 256, 0, stream>>>(rp2, ebuf, y2, dinv, b2, h2);

    // ---- layer 3: 32 -> 2 + log_softmax ----
    k_gemm_scale<H2, COUT, 128><<<(N + 127) / 128, dim3(COUT, 128), 0, stream>>>(h2, W3, dinv, y3);
    k_final<<<(N + 127) / 128, dim3(2, 128), 0, stream>>>(rp2, ebuf, y3, dinv, b3, out);
}

// Round 4
// 380.512 us; speedup vs baseline: 5.3448x; 1.7491x over previous
//
#include <hip/hip_runtime.h>
#include <hip/hip_bf16.h>
#include <math.h>

// Problem constants (from reference)
constexpr int N = 100000;    // nodes
constexpr int E = 3200000;   // edges
constexpr int FIN = 128, H1 = 64, H2 = 32, COUT = 2;

// Bucketing: 64 dst-nodes per bucket, fixed-capacity slices
constexpr int BUK_SHIFT = 6;
constexpr int BUK_NODES = 64;                          // 1 << BUK_SHIFT
constexpr int NBUK = (N + BUK_NODES - 1) / BUK_NODES;  // 1563
constexpr int CAP = 2560;             // slice capacity; mean fill 2048, sigma~45
// src segmentation: seg = src >> 14. Keys are LD-MAJOR (key = ld*7 + seg):
// each node's list is contiguous AND seg-sorted within (R0's proven layout —
// implicit temporal seg-sweep, FETCH 290MB, 89.5us).
// R1-R3 lessons: explicit seg-phasing breaks either MLP (short sublists) or
// scheduler batching (branches/atomics between gathers serialize: VGPR 12-24,
// VALUBusy 2-12%). Gather MLP survives ONLY pure-arithmetic consumers.
// R4 lever: 16B uint4 gathers (8 bf16/lane) -> 4x fewer gather addresses
// (TA/L1 address throughput is the R0 bottleneck hypothesis).
constexpr int SEG_SHIFT = 14;
constexpr int NSEG = 7;
constexpr int KEYS = BUK_NODES * NSEG;                 // 448 (ld-major!)
constexpr int RP_STR = BUK_NODES + 1;                  // 65 rowptr slots per bucket

constexpr int MS_TPB = 1024;
constexpr int MS_EPT = 24;                             // edges per thread
constexpr int CHUNK = MS_TPB * MS_EPT;                 // 24576
constexpr int MS_WGS = (E + CHUNK - 1) / CHUNK;        // 131

// ---------------- init: gcursor[b] = b*CAP ----------------
__global__ void k_initcur(int* __restrict__ gcursor) {
    int i = blockIdx.x * blockDim.x + threadIdx.x;
    if (i < NBUK) gcursor[i] = i * CAP;
}

// ---------------- multisplit into fixed-capacity bucket slices ----------------
// packed entry: src (17 bits) | local_node (6 bits) << 17
__global__ __launch_bounds__(MS_TPB)
void k_mslice(const int* __restrict__ src, const int* __restrict__ dst,
              int* __restrict__ gcursor, unsigned* __restrict__ ebuf) {
    __shared__ int cnt[NBUK];
    __shared__ int base[NBUK];
    const int t = threadIdx.x;
    for (int i = t; i < NBUK; i += MS_TPB) cnt[i] = 0;
    __syncthreads();
    const int e0 = blockIdx.x * CHUNK;

    int rb[MS_EPT];
    unsigned rv[MS_EPT];
#pragma unroll
    for (int j = 0; j < MS_EPT; ++j) {
        int e = e0 + j * MS_TPB + t;
        if (e < E) {
            int d = dst[e];
            int b = d >> BUK_SHIFT;
            rb[j] = b;
            rv[j] = (unsigned)src[e] | ((unsigned)(d & (BUK_NODES - 1)) << 17);
            atomicAdd(&cnt[b], 1);
        } else {
            rb[j] = -1; rv[j] = 0;
        }
    }
    __syncthreads();
    for (int i = t; i < NBUK; i += MS_TPB) {
        int c = cnt[i];
        base[i] = c ? atomicAdd(&gcursor[i], c) : 0;
    }
    __syncthreads();
    for (int i = t; i < NBUK; i += MS_TPB) cnt[i] = 0;
    __syncthreads();
#pragma unroll
    for (int j = 0; j < MS_EPT; ++j) {
        int b = rb[j];
        if (b >= 0) {
            int r = atomicAdd(&cnt[b], 1);
            int p = base[b] + r;
            if (p < (b + 1) * CAP) ebuf[p] = rv[j];   // overflow guard (statistically impossible)
        }
    }
}

// ---------------- per-bucket build: counting-sort by (local_dst, seg) ----------------
// ld-major key => each node's list is contiguous AND seg-sorted within.
// Emits rp[b*65 + ld] = node list start, rp[b*65+64] = slice end; dinv.
__global__ __launch_bounds__(256)
void k_build(const int* __restrict__ gcursor, unsigned* __restrict__ ebuf,
             int* __restrict__ rp, float* __restrict__ dinv) {
    __shared__ unsigned ent[CAP];
    __shared__ int cnt[512];
    __shared__ int sa[512];
    __shared__ int sb[512];
    __shared__ int cur[512];
    const int b = blockIdx.x;
    const int t = threadIdx.x;
    int fill = gcursor[b] - b * CAP;
    if (fill > CAP) fill = CAP;
    const int gbase = b * CAP;

    cnt[t] = 0; cnt[t + 256] = 0;
    __syncthreads();
    for (int j = t; j < fill; j += 256) {
        unsigned v = ebuf[gbase + j];
        ent[j] = v;
        int key = (int)(v >> 17) * NSEG + (int)((v & 0x1FFFFu) >> SEG_SHIFT);
        atomicAdd(&cnt[key], 1);
    }
    __syncthreads();
    sa[t] = cnt[t]; sa[t + 256] = cnt[t + 256];
    __syncthreads();
    int* pin = sa; int* pout = sb;
    for (int off = 1; off < 512; off <<= 1) {
        pout[t]       = pin[t]       + ((t >= off)       ? pin[t - off]       : 0);
        pout[t + 256] = pin[t + 256] + ((t + 256 >= off) ? pin[t + 256 - off] : 0);
        __syncthreads();
        int* tmp = pin; pin = pout; pout = tmp;
    }
    {
        int ex0 = pin[t] - cnt[t];
        int ex1 = pin[t + 256] - cnt[t + 256];
        cur[t] = gbase + ex0;
        cur[t + 256] = gbase + ex1;
        // node list start = start of its first (seg=0) key
        if (t < KEYS && (t % NSEG) == 0)
            rp[b * RP_STR + t / NSEG] = gbase + ex0;
        int k2 = t + 256;
        if (k2 < KEYS && (k2 % NSEG) == 0)
            rp[b * RP_STR + k2 / NSEG] = gbase + ex1;
        if (t == 0) rp[b * RP_STR + BUK_NODES] = gbase + fill;   // sentinel
    }
    if (t < BUK_NODES) {
        int deg = 0;
#pragma unroll
        for (int s = 0; s < NSEG; ++s) deg += cnt[t * NSEG + s];
        int node = (b << BUK_SHIFT) + t;
        if (node < N) dinv[node] = rsqrtf((float)deg + 1.0f);  // self-loop included
    }
    __syncthreads();
    for (int j = t; j < fill; j += 256) {
        unsigned v = ent[j];
        int key = (int)(v >> 17) * NSEG + (int)((v & 0x1FFFFu) >> SEG_SHIFT);
        int p = atomicAdd(&cur[key], 1);
        ebuf[p] = v & 0x1FFFFu;   // sorted, plain src
    }
}

// ---------------- register-tiled GEMM + dinv scale, bf16 output ----------------
template<int FI, int FO>
__global__ __launch_bounds__(256)
void k_gemm_tile_bf(const float* __restrict__ h, const float* __restrict__ Wg,
                    const float* __restrict__ dinv, __hip_bfloat16* __restrict__ y) {
    constexpr int TX  = FO / 4;
    constexpr int TY  = 256 / TX;
    constexpr int RPT = 64 / TY;
    constexpr int XS  = 68;
    constexpr int KQ  = FI / 4;

    __shared__ float xsT[FI][XS];

    const int tid = threadIdx.x;
    const int tx = tid % TX;
    const int ty = tid / TX;
    const int row0 = blockIdx.x * 64;

    for (int idx = tid; idx < 64 * KQ; idx += 256) {
        int g   = idx / 8;
        int rlo = idx % 8;
        int k4  = g % KQ;
        int rhi = g / KQ;
        int r   = rlo + 8 * rhi;
        int row = row0 + r;
        float4 v = make_float4(0.f, 0.f, 0.f, 0.f);
        if (row < N) v = *(const float4*)(h + (size_t)row * FI + 4 * k4);
        xsT[4 * k4 + 0][r] = v.x;
        xsT[4 * k4 + 1][r] = v.y;
        xsT[4 * k4 + 2][r] = v.z;
        xsT[4 * k4 + 3][r] = v.w;
    }
    __syncthreads();

    float acc[RPT][4];
#pragma unroll
    for (int i = 0; i < RPT; ++i)
#pragma unroll
        for (int c = 0; c < 4; ++c) acc[i][c] = 0.0f;

#pragma unroll 4
    for (int k = 0; k < FI; ++k) {
        const float4 wv = *(const float4*)(Wg + (size_t)k * FO + 4 * tx);
        float xv[RPT];
        if constexpr (RPT == 4) {
            float4 t = *(const float4*)&xsT[k][4 * ty];
            xv[0] = t.x; xv[1] = t.y; xv[2] = t.z; xv[3] = t.w;
        } else {
            float2 t = *(const float2*)&xsT[k][2 * ty];
            xv[0] = t.x; xv[1] = t.y;
        }
#pragma unroll
        for (int i = 0; i < RPT; ++i) {
            acc[i][0] = fmaf(xv[i], wv.x, acc[i][0]);
            acc[i][1] = fmaf(xv[i], wv.y, acc[i][1]);
            acc[i][2] = fmaf(xv[i], wv.z, acc[i][2]);
            acc[i][3] = fmaf(xv[i], wv.w, acc[i][3]);
        }
    }

#pragma unroll
    for (int i = 0; i < RPT; ++i) {
        int row = row0 + ty * RPT + i;
        if (row >= N) continue;
        float di = dinv[row];
        auto cvt = [](float f) -> unsigned short {
            __hip_bfloat16 b = __float2bfloat16(f);
            return *reinterpret_cast<unsigned short*>(&b);
        };
        ushort4 pk;
        pk.x = cvt(di * acc[i][0]);
        pk.y = cvt(di * acc[i][1]);
        pk.z = cvt(di * acc[i][2]);
        pk.w = cvt(di * acc[i][3]);
        *(ushort4*)&y[(size_t)row * FO + 4 * tx] = pk;
    }
}

// ---------------- fused GEMM + dinv scale, fp32 output (layer 3, tiny) ----------------
template<int FI, int FO, int ROWS>
__global__ __launch_bounds__(FO * ROWS)
void k_gemm_scale(const float* __restrict__ h, const float* __restrict__ W,
                  const float* __restrict__ dinv, float* __restrict__ y) {
    __shared__ float xs[ROWS][FI];
    const int j = threadIdx.x;
    const int r = threadIdx.y;
    const int row0 = blockIdx.x * ROWS;
    const int tid = r * FO + j;
    constexpr int NT = FO * ROWS;
    for (int t = tid; t < ROWS * FI; t += NT) {
        int rr = t / FI, kk = t % FI;
        int row = row0 + rr;
        xs[rr][kk] = (row < N) ? h[(size_t)row * FI + kk] : 0.0f;
    }
    __syncthreads();
    const int row = row0 + r;
    if (row >= N) return;
    float acc = 0.0f;
#pragma unroll
    for (int k = 0; k < FI; ++k)
        acc = fmaf(xs[r][k], W[k * FO + j], acc);
    y[(size_t)row * FO + j] = dinv[row] * acc;
}

// ---------------- CSR aggregate, 16B vectorized gather + fused epilogue -------
// R0's proven flat per-node walk, widened: each lane owns 8 bf16 features
// (one uint4 = quarter/half row), so an edge costs LPN={8,4} gather addresses
// instead of {32,16}. Branch-free 8-deep batch (named regs) for MLP;
// consumers are pure unpack+add (the only form the scheduler keeps in flight).
template<int F, bool RELU>
__global__ __launch_bounds__(256)
void k_agg_v(const int* __restrict__ rp, const unsigned* __restrict__ csr,
             const __hip_bfloat16* __restrict__ y, const float* __restrict__ dinv,
             const float* __restrict__ b, float* __restrict__ out) {
    constexpr int LPN = F / 8;         // lanes per node (uint4 slots per row)
    constexpr int NPB = 256 / LPN;     // nodes per block
    const int fp = threadIdx.x;        // uint4 slot index within row
    const int n = blockIdx.x * NPB + threadIdx.y;
    if (n >= N) return;
    const uint4* yq = (const uint4*)y;          // row stride = LPN uint4s

    float acc[8];
    auto unpk = [](unsigned w, float& lo, float& hi) {
        lo = __uint_as_float(w << 16);
        hi = __uint_as_float(w & 0xffff0000u);
    };
    auto accum = [&](uint4 v) {
        float l0, h0, l1, h1, l2, h2, l3, h3;
        unpk(v.x, l0, h0); unpk(v.y, l1, h1);
        unpk(v.z, l2, h2); unpk(v.w, l3, h3);
        acc[0] += l0; acc[1] += h0; acc[2] += l1; acc[3] += h1;
        acc[4] += l2; acc[5] += h2; acc[6] += l3; acc[7] += h3;
    };

    // self-loop init
    {
        uint4 v = yq[(size_t)n * LPN + fp];
        float l0, h0, l1, h1, l2, h2, l3, h3;
        unpk(v.x, l0, h0); unpk(v.y, l1, h1);
        unpk(v.z, l2, h2); unpk(v.w, l3, h3);
        acc[0] = l0; acc[1] = h0; acc[2] = l1; acc[3] = h1;
        acc[4] = l2; acc[5] = h2; acc[6] = l3; acc[7] = h3;
    }

    const int rb = (n >> BUK_SHIFT) * RP_STR + (n & (BUK_NODES - 1));
    int j = rp[rb];
    const int j1 = rp[rb + 1];
    for (; j + 8 <= j1; j += 8) {   // 8 x 16B gathers in flight per lane
        int s0 = (int)csr[j],     s1 = (int)csr[j + 1], s2 = (int)csr[j + 2], s3 = (int)csr[j + 3];
        int s4 = (int)csr[j + 4], s5 = (int)csr[j + 5], s6 = (int)csr[j + 6], s7 = (int)csr[j + 7];
        uint4 v0 = yq[(size_t)s0 * LPN + fp], v1 = yq[(size_t)s1 * LPN + fp];
        uint4 v2 = yq[(size_t)s2 * LPN + fp], v3 = yq[(size_t)s3 * LPN + fp];
        uint4 v4 = yq[(size_t)s4 * LPN + fp], v5 = yq[(size_t)s5 * LPN + fp];
        uint4 v6 = yq[(size_t)s6 * LPN + fp], v7 = yq[(size_t)s7 * LPN + fp];
        accum(v0); accum(v1); accum(v2); accum(v3);
        accum(v4); accum(v5); accum(v6); accum(v7);
    }
    for (; j < j1; ++j) {
        uint4 v = yq[(size_t)(int)csr[j] * LPN + fp];
        accum(v);
    }

    const float di = dinv[n];
    float4 o0, o1;
    o0.x = fmaf(di, acc[0], b[8 * fp + 0]);
    o0.y = fmaf(di, acc[1], b[8 * fp + 1]);
    o0.z = fmaf(di, acc[2], b[8 * fp + 2]);
    o0.w = fmaf(di, acc[3], b[8 * fp + 3]);
    o1.x = fmaf(di, acc[4], b[8 * fp + 4]);
    o1.y = fmaf(di, acc[5], b[8 * fp + 5]);
    o1.z = fmaf(di, acc[6], b[8 * fp + 6]);
    o1.w = fmaf(di, acc[7], b[8 * fp + 7]);
    if (RELU) {
        o0.x = fmaxf(o0.x, 0.f); o0.y = fmaxf(o0.y, 0.f);
        o0.z = fmaxf(o0.z, 0.f); o0.w = fmaxf(o0.w, 0.f);
        o1.x = fmaxf(o1.x, 0.f); o1.y = fmaxf(o1.y, 0.f);
        o1.z = fmaxf(o1.z, 0.f); o1.w = fmaxf(o1.w, 0.f);
    }
    float* op = out + (size_t)n * F + 8 * fp;
    *(float4*)op = o0;
    *(float4*)(op + 4) = o1;
}

// ---------------- layer 3 aggregate + log_softmax (2 classes) ----------------
__global__ __launch_bounds__(256)
void k_final(const int* __restrict__ rp, const unsigned* __restrict__ csr,
             const float* __restrict__ y, const float* __restrict__ dinv,
             const float* __restrict__ bias, float* __restrict__ out) {
    const int c = threadIdx.x;                       // class 0/1
    const int n = blockIdx.x * 128 + threadIdx.y;    // node
    float z = 0.0f;
    if (n < N) {
        const int rb = (n >> BUK_SHIFT) * RP_STR + (n & (BUK_NODES - 1));
        int j = rp[rb];
        const int j1 = rp[rb + 1];
        float acc = y[2 * n + c];
        for (; j + 4 <= j1; j += 4) {
            int s0 = (int)csr[j], s1 = (int)csr[j + 1], s2 = (int)csr[j + 2], s3 = (int)csr[j + 3];
            float a0 = y[2 * s0 + c], a1 = y[2 * s1 + c];
            float a2 = y[2 * s2 + c], a3 = y[2 * s3 + c];
            acc += (a0 + a1) + (a2 + a3);
        }
        for (; j < j1; ++j) acc += y[2 * (int)csr[j] + c];
        z = fmaf(dinv[n], acc, bias[c]);
    }
    float zo = __shfl_xor(z, 1);
    if (n < N) {
        float m = fmaxf(z, zo);
        float lse = m + logf(expf(z - m) + expf(zo - m));
        out[2 * n + c] = z - lse;
    }
}

extern "C" void kernel_launch(void* const* d_in, const int* in_sizes, int n_in,
                              void* d_out, int out_size, void* d_ws, size_t ws_size,
                              hipStream_t stream) {
    const float* x   = (const float*)d_in[0];
    const int*   ei  = (const int*)d_in[1];
    const float* W1  = (const float*)d_in[2];
    const float* b1  = (const float*)d_in[3];
    const float* W2  = (const float*)d_in[4];
    const float* b2  = (const float*)d_in[5];
    const float* W3  = (const float*)d_in[6];
    const float* b3  = (const float*)d_in[7];
    float* out = (float*)d_out;

    const int* src = ei;
    const int* dst = ei + E;

    // workspace layout
    char* p = (char*)d_ws;
    float*    dinv    = (float*)p;    p += (size_t)N * 4;
    int*      gcursor = (int*)p;      p += (size_t)NBUK * 4;
    int*      rp      = (int*)p;      p += (size_t)NBUK * RP_STR * 4;  // 406 KB
    unsigned* ebuf    = (unsigned*)p; p += (size_t)NBUK * CAP * 4;     // 16 MB
    char*     bufA    = p;            p += (size_t)N * 64 * 4;         // 25.6 MB
    char*     bufB    = p;            p += (size_t)N * 64 * 4;         // 25.6 MB

    __hip_bfloat16* y1 = (__hip_bfloat16*)bufA;     // N*64*2 B
    float*          h1 = (float*)bufB;              // N*64*4 B
    __hip_bfloat16* y2 = (__hip_bfloat16*)bufA;     // N*32*2 B (y1 dead)
    float*          h2 = (float*)(bufA + (size_t)N * H2 * 2);  // N*32*4 B
    float*          y3 = (float*)bufB;              // N*2*4 B (h1 dead)

    // ---- edge structure build ----
    k_initcur<<<(NBUK + 255) / 256, 256, 0, stream>>>(gcursor);
    k_mslice <<<MS_WGS, MS_TPB, 0, stream>>>(src, dst, gcursor, ebuf);
    k_build  <<<NBUK, 256, 0, stream>>>(gcursor, ebuf, rp, dinv);

    // ---- layer 1: 128 -> 64 ----
    k_gemm_tile_bf<FIN, H1><<<(N + 63) / 64, 256, 0, stream>>>(x, W1, dinv, y1);
    k_agg_v<H1, true><<<(N + 31) / 32, dim3(8, 32), 0, stream>>>(rp, ebuf, y1, dinv, b1, h1);

    // ---- layer 2: 64 -> 32 ----
    k_gemm_tile_bf<H1, H2><<<(N + 63) / 64, 256, 0, stream>>>(h1, W2, dinv, y2);
    k_agg_v<H2, true><<<(N + 63) / 64, dim3(4, 64), 0, stream>>>(rp, ebuf, y2, dinv, b2, h2);

    // ---- layer 3: 32 -> 2 + log_softmax ----
    k_gemm_scale<H2, COUT, 128><<<(N + 127) / 128, dim3(COUT, 128), 0, stream>>>(h2, W3, dinv, y3);
    k_final<<<(N + 127) / 128, dim3(2, 128), 0, stream>>>(rp, ebuf, y3, dinv, b3, out);
}